// Round 2
// baseline (304.672 us; speedup 1.0000x reference)
//
#include <hip/hip_runtime.h>

// Trilinear resize [4,128,128,128,2] f32 -> [4,192,192,192,2] f32.
// zoom = 1.5 exactly => weights periodic with period 3 outputs / 2 inputs:
//   output o: m = o/3, r = o%3; i0 = 2m + (r==2); i1 = min(i0+1,127);
//   w0 = {1, 1/3, 2/3}[r]; w1 = 1-w0.
//
// Each thread owns (b, y, x-pair) and marches 8 z-triples, carrying the
// shared input plane's x/y-lerped value in registers (adjacent triples
// share plane 2zt+2 == 2(zt+1)): 12 new float2 loads per 3 output planes
// instead of 18.
// Block swizzle: each XCD gets 4 private (batch, z-slab) combos so input
// slabs (17 planes ~ 2.2 MB) stay resident in that XCD's L2 and are
// HBM-fetched once chip-wide. Output uses nontemporal stores so the
// 226 MB write stream doesn't evict input slabs from L2.

#define IN_D  128
#define OUT_D 192
#define OUT_XP 96
#define ZT_PER_THREAD 8   // z-triples per thread (24 output z per thread)
#define NCHUNK 8          // 64 triples / ZT_PER_THREAD

typedef float nfloat4 __attribute__((ext_vector_type(4)));

__global__ __launch_bounds__(192) void resize_trilinear_kernel(
        const float2* __restrict__ in, float4* __restrict__ out) {
    // ---- bijective XCD swizzle over the 3072-block grid ----
    // linear id -> (xcd = g%8, j = g/8); each xcd owns combos [4*xcd, 4*xcd+4)
    // combo in [0,32) = (zc in [0,8), b in [0,4)); ypair = j%96.
    int g = (int)(blockIdx.x + gridDim.x * (blockIdx.y + gridDim.y * blockIdx.z));
    int xcd   = g & 7;
    int j     = g >> 3;          // 0..383
    int cj    = j / 96;          // 0..3
    int ypair = j - cj * 96;     // 0..95
    int combo = xcd * 4 + cj;    // 0..31
    int zc = combo & 7;          // z-chunk 0..7
    int b  = combo >> 3;         // batch 0..3

    const int xp = (int)threadIdx.x;                 // 0..95 (x output pair)
    const int y  = ypair * 2 + (int)threadIdx.y;     // 0..191

    const float THIRD = 0.33333334f;
    const float TWO3  = 0.66666669f;

    // ---- x pair (x = 2*xp, 2*xp+1) ----
    unsigned xo = 2u * (unsigned)xp;
    unsigned mx = xo / 3u;               // magic-mul
    unsigned rx = xo - 3u * mx;
    int xbase = 2 * (int)mx + (rx == 2u ? 1 : 0);
    int xi1 = min(xbase + 1, IN_D - 1);
    int xi2 = min(xbase + 2, IN_D - 1);
    float wxa0 = (rx == 0u) ? 1.0f : ((rx == 1u) ? THIRD : TWO3);
    float wxa1 = 1.0f - wxa0;
    float wxb0 = (rx == 0u) ? THIRD : ((rx == 1u) ? TWO3 : 1.0f);
    float wxb1 = 1.0f - wxb0;
    bool sel = (rx != 0u);

    // ---- y ----
    unsigned uy = (unsigned)y;
    unsigned my = uy / 3u;
    unsigned ry = uy - 3u * my;
    int y0 = 2 * (int)my + (ry == 2u ? 1 : 0);
    int y1 = min(y0 + 1, IN_D - 1);
    float wy0 = (ry == 0u) ? 1.0f : ((ry == 1u) ? THIRD : TWO3);
    float wy1 = 1.0f - wy0;

    const float2* basep = in + (size_t)b * (IN_D * IN_D * IN_D);

    // x/y-lerp one input plane -> the thread's x-pair result (U0,U1)
    auto plane_u = [&](int pz, float2& U0, float2& U1) {
        const float2* rA = basep + (size_t)(pz * IN_D + y0) * IN_D;
        const float2* rB = basep + (size_t)(pz * IN_D + y1) * IN_D;
        float2 a0 = rA[xbase], a1 = rA[xi1], a2 = rA[xi2];
        float2 b0 = rB[xbase], b1 = rB[xi1], b2 = rB[xi2];
        float2 V0, V1, V2;
        V0.x = a0.x * wy0 + b0.x * wy1;  V0.y = a0.y * wy0 + b0.y * wy1;
        V1.x = a1.x * wy0 + b1.x * wy1;  V1.y = a1.y * wy0 + b1.y * wy1;
        V2.x = a2.x * wy0 + b2.x * wy1;  V2.y = a2.y * wy0 + b2.y * wy1;
        U0.x = V0.x * wxa0 + V1.x * wxa1;
        U0.y = V0.y * wxa0 + V1.y * wxa1;
        float2 c0 = sel ? V1 : V0;
        float2 c1 = sel ? V2 : V1;
        U1.x = c0.x * wxb0 + c1.x * wxb1;
        U1.y = c0.y * wxb0 + c1.y * wxb1;
    };

    auto nt_store = [&](size_t idx, float4 v) {
        nfloat4 nv;
        nv.x = v.x; nv.y = v.y; nv.z = v.z; nv.w = v.w;
        __builtin_nontemporal_store(nv, (nfloat4*)&out[idx]);
    };

    // ---- z march over ZT_PER_THREAD triples; carry shared plane in regs ----
    const int zt0 = zc * ZT_PER_THREAD;
    float2 uA0, uA1;                       // plane 2*zt (carried)
    plane_u(2 * zt0, uA0, uA1);

    const size_t zs = (size_t)OUT_D * OUT_XP;
    size_t ob = (((size_t)b * OUT_D + 3 * zt0) * OUT_D + y) * OUT_XP + xp;

#pragma unroll 2
    for (int t = 0; t < ZT_PER_THREAD; ++t) {
        const int zt = zt0 + t;
        float2 uB0, uB1, uC0, uC1;
        plane_u(2 * zt + 1, uB0, uB1);                 // plane 2zt+1
        plane_u(min(2 * zt + 2, IN_D - 1), uC0, uC1);  // plane 2zt+2 (clipped)

        float4 o0, o1, o2;
        o0.x = uA0.x;  o0.y = uA0.y;  o0.z = uA1.x;  o0.w = uA1.y;
        o1.x = uA0.x * THIRD + uB0.x * TWO3;
        o1.y = uA0.y * THIRD + uB0.y * TWO3;
        o1.z = uA1.x * THIRD + uB1.x * TWO3;
        o1.w = uA1.y * THIRD + uB1.y * TWO3;
        o2.x = uB0.x * TWO3 + uC0.x * THIRD;
        o2.y = uB0.y * TWO3 + uC0.y * THIRD;
        o2.z = uB1.x * TWO3 + uC1.x * THIRD;
        o2.w = uB1.y * TWO3 + uC1.y * THIRD;

        nt_store(ob, o0);
        nt_store(ob + zs, o1);
        nt_store(ob + 2 * zs, o2);
        ob += 3 * zs;

        uA0 = uC0; uA1 = uC1;              // plane 2(zt+1) = old plane 2zt+2
    }
}

extern "C" void kernel_launch(void* const* d_in, const int* in_sizes, int n_in,
                              void* d_out, int out_size, void* d_ws, size_t ws_size,
                              hipStream_t stream) {
    const float2* in = (const float2*)d_in[0];
    float4* out = (float4*)d_out;

    dim3 block(OUT_XP, 2, 1);        // 192 threads = 3 waves
    dim3 grid(OUT_D / 2, NCHUNK, 4); // 96 y-pairs x 8 z-chunks x 4 batch = 3072 blocks

    resize_trilinear_kernel<<<grid, block, 0, stream>>>(in, out);
}

// Round 3
// 284.588 us; speedup vs baseline: 1.0706x; 1.0706x over previous
//
#include <hip/hip_runtime.h>

// Trilinear resize [4,128,128,128,2] f32 -> [4,192,192,192,2] f32.
// zoom = 1.5 exactly => per axis, weights are periodic with period
// 3 outputs / 2 inputs: output o = 3m+r: i0 = 2m + (r==2);
// w0 = {1, 1/3, 2/3}[r]; w1 = 1-w0.
//
// v3: input reads are BLOCK-PRIVATE by construction (no reliance on L2/L3
// reuse — the harness's 864 MiB poison fill flushes both every iteration).
// Each thread owns an output brick: x-pair (float4 of 2 outputs x 2ch)
// times y-TRIPLE (3 outputs from 3 input rows) times a z-march of 4
// z-triples (carrying the shared plane's x/y-lerped float4[3] in regs).
// Per plane the thread loads 3 rows x 3 x-positions = 9 float2 and emits
// all 3 y-outputs; per z-step: 18 float2 loaded, 9 float4 stored
// (1:1 bytes). Chip-wide HBM input traffic ~= 90 MB regardless of cache
// state. Output via nontemporal stores (pure stream).

#define IN_D  128
#define OUT_D 192
#define OUT_XP 96
#define YT_PER_BLOCK 2   // y-triples per block (block covers 6 output y)
#define ZT_PER_CHUNK 4   // z-triples marched per thread (12 output z)
#define NZC 16           // 64 z-triples / ZT_PER_CHUNK

typedef float nfloat4 __attribute__((ext_vector_type(4)));

__device__ __forceinline__ float4 f4lerp(float4 a, float4 b, float wa, float wb) {
    float4 r;
    r.x = a.x * wa + b.x * wb;
    r.y = a.y * wa + b.y * wb;
    r.z = a.z * wa + b.z * wb;
    r.w = a.w * wa + b.w * wb;
    return r;
}

__global__ __launch_bounds__(192) void resize_trilinear_kernel(
        const float2* __restrict__ in, float4* __restrict__ out) {
    const int xp = (int)threadIdx.x;                              // 0..95
    const int yt = (int)(blockIdx.x * YT_PER_BLOCK + threadIdx.y); // 0..63 (y-triple)
    const int zc = (int)blockIdx.y;                               // 0..15 (z-chunk)
    const int b  = (int)blockIdx.z;                               // 0..3

    const float THIRD = 0.33333334f;
    const float TWO3  = 0.66666669f;

    // ---- x pair (outputs x = 2*xp, 2*xp+1) ----
    unsigned xo = 2u * (unsigned)xp;
    unsigned mx = xo / 3u;               // magic-mul
    unsigned rx = xo - 3u * mx;
    int xbase = 2 * (int)mx + (rx == 2u ? 1 : 0);
    int xi1 = min(xbase + 1, IN_D - 1);
    int xi2 = min(xbase + 2, IN_D - 1);
    float wxa0 = (rx == 0u) ? 1.0f : ((rx == 1u) ? THIRD : TWO3);
    float wxa1 = 1.0f - wxa0;
    float wxb0 = (rx == 0u) ? THIRD : ((rx == 1u) ? TWO3 : 1.0f);
    float wxb1 = 1.0f - wxb0;
    bool sel = (rx != 0u);

    // ---- y triple (outputs y = 3*yt .. 3*yt+2 from rows 2yt..2yt+2) ----
    const int yr0 = 2 * yt;
    const int yr1 = yr0 + 1;
    const int yr2 = min(yr0 + 2, IN_D - 1);

    const float2* basep = in + (size_t)b * (IN_D * IN_D * IN_D);

    // x-lerp one input row -> float4 (2 outputs x 2 ch)
    auto row_x = [&](const float2* __restrict__ r) -> float4 {
        float2 a0 = r[xbase], a1 = r[xi1], a2 = r[xi2];
        float2 c0 = sel ? a1 : a0;
        float2 c1 = sel ? a2 : a1;
        float4 X;
        X.x = a0.x * wxa0 + a1.x * wxa1;
        X.y = a0.y * wxa0 + a1.y * wxa1;
        X.z = c0.x * wxb0 + c1.x * wxb1;
        X.w = c0.y * wxb0 + c1.y * wxb1;
        return X;
    };

    // x+y lerp one input plane -> U[3] (y-triple of x-pair float4s)
    auto plane_u = [&](int pz, float4 U[3]) {
        const float2* p = basep + (size_t)pz * (IN_D * IN_D);
        float4 X0 = row_x(p + (size_t)yr0 * IN_D);
        float4 X1 = row_x(p + (size_t)yr1 * IN_D);
        float4 X2 = row_x(p + (size_t)yr2 * IN_D);
        U[0] = X0;                            // out y=3yt   : w = {1, 0}
        U[1] = f4lerp(X0, X1, THIRD, TWO3);   // out y=3yt+1 : rows (2yt, 2yt+1)
        U[2] = f4lerp(X1, X2, TWO3, THIRD);   // out y=3yt+2 : rows (2yt+1, 2yt+2)
    };

    auto nt_store = [&](size_t idx, float4 v) {
        nfloat4 nv;
        nv.x = v.x; nv.y = v.y; nv.z = v.z; nv.w = v.w;
        __builtin_nontemporal_store(nv, (nfloat4*)&out[idx]);
    };

    // ---- z march: triples zt0..zt0+3, carrying shared plane in regs ----
    const int zt0 = zc * ZT_PER_CHUNK;
    float4 UA[3];
    plane_u(2 * zt0, UA);                     // plane 2*zt (carried)

    const size_t zs = (size_t)OUT_D * OUT_XP; // one output z-plane
    size_t ob = (((size_t)b * OUT_D + 3 * zt0) * OUT_D + 3 * yt) * OUT_XP + xp;

#pragma unroll
    for (int t = 0; t < ZT_PER_CHUNK; ++t) {
        const int zt = zt0 + t;
        float4 UB[3], UC[3];
        plane_u(2 * zt + 1, UB);                  // plane 2zt+1
        plane_u(min(2 * zt + 2, IN_D - 1), UC);   // plane 2zt+2 (clipped)

#pragma unroll
        for (int yi = 0; yi < 3; ++yi) {
            float4 o0 = UA[yi];                               // z=3zt
            float4 o1 = f4lerp(UA[yi], UB[yi], THIRD, TWO3);  // z=3zt+1
            float4 o2 = f4lerp(UB[yi], UC[yi], TWO3, THIRD);  // z=3zt+2
            size_t oy = ob + (size_t)yi * OUT_XP;
            nt_store(oy,          o0);
            nt_store(oy + zs,     o1);
            nt_store(oy + 2 * zs, o2);
        }
        ob += 3 * zs;
        UA[0] = UC[0]; UA[1] = UC[1]; UA[2] = UC[2];  // plane 2(zt+1) = old 2zt+2
    }
}

extern "C" void kernel_launch(void* const* d_in, const int* in_sizes, int n_in,
                              void* d_out, int out_size, void* d_ws, size_t ws_size,
                              hipStream_t stream) {
    const float2* in = (const float2*)d_in[0];
    float4* out = (float4*)d_out;

    dim3 block(OUT_XP, YT_PER_BLOCK, 1);   // 192 threads = 3 waves
    dim3 grid(64 / YT_PER_BLOCK, NZC, 4);  // 32 y-blocks x 16 z-chunks x 4 batch = 2048
    resize_trilinear_kernel<<<grid, block, 0, stream>>>(in, out);
}

// Round 4
// 278.545 us; speedup vs baseline: 1.0938x; 1.0217x over previous
//
#include <hip/hip_runtime.h>

// Trilinear resize [4,128,128,128,2] f32 -> [4,192,192,192,2] f32.
// zoom = 1.5 exactly => per axis, weights are periodic with period
// 3 outputs / 2 inputs: output o = 3m+r: i0 = 2m + (r==2);
// w0 = {1, 1/3, 2/3}[r]; w1 = 1-w0.
//
// v4: read path rebuilt. All input loads are ALIGNED 16B (float4 = 2
// voxels x 2ch). For the x-pair owned by a thread, the 3 needed input
// voxels always lie in the aligned 4-voxel window [2mx, 2mx+3]
// -> 2 aligned dwordx4 per row (was 3 unaligned dwordx2).
// Per z-step, all 12 loads (2 planes x 3 rows x 2 quads) issue before
// any compute -> deep MLP. Everything else as v3: block-private input
// (x-pair x y-triple x z-march-of-4 brick per thread), register-carried
// shared plane, nontemporal float4 stores.

#define IN_D  128
#define OUT_D 192
#define OUT_XP 96
#define YT_PER_BLOCK 2   // y-triples per block (block covers 6 output y)
#define ZT_PER_CHUNK 4   // z-triples marched per thread (12 output z)
#define NZC 16           // 64 z-triples / ZT_PER_CHUNK
#define ROW_Q 64         // input row length in float4 units (128 float2)

typedef float nfloat4 __attribute__((ext_vector_type(4)));

__device__ __forceinline__ float4 f4lerp(float4 a, float4 b, float wa, float wb) {
    float4 r;
    r.x = a.x * wa + b.x * wb;
    r.y = a.y * wa + b.y * wb;
    r.z = a.z * wa + b.z * wb;
    r.w = a.w * wa + b.w * wb;
    return r;
}

__global__ __launch_bounds__(192) void resize_trilinear_kernel(
        const float4* __restrict__ in4, float4* __restrict__ out) {
    const int xp = (int)threadIdx.x;                               // 0..95
    const int yt = (int)(blockIdx.x * YT_PER_BLOCK + threadIdx.y); // 0..63
    const int zc = (int)blockIdx.y;                                // 0..15
    const int b  = (int)blockIdx.z;                                // 0..3

    const float THIRD = 0.33333334f;
    const float TWO3  = 0.66666669f;

    // ---- x pair (outputs x = 2*xp, 2*xp+1) ----
    unsigned xo = 2u * (unsigned)xp;
    unsigned mx = xo / 3u;               // magic-mul
    unsigned rx = xo - 3u * mx;
    // aligned quad offsets within a row (float4 units): window [2mx, 2mx+3]
    const int q0o = (int)mx;
    const bool clip = (mx == 63u);       // xp==95: clamp second quad into row
    const int q1o = clip ? 63 : (int)mx + 1;
    float wxa0 = (rx == 0u) ? 1.0f : ((rx == 1u) ? THIRD : TWO3);
    float wxa1 = 1.0f - wxa0;
    float wxb0 = (rx == 0u) ? THIRD : ((rx == 1u) ? TWO3 : 1.0f);
    float wxb1 = 1.0f - wxb0;

    // ---- y triple (outputs y = 3*yt .. 3*yt+2 from rows 2yt..2yt+2) ----
    const int yr0 = 2 * yt;
    const int yr1 = yr0 + 1;
    const int yr2 = min(yr0 + 2, IN_D - 1);

    const float4* basep = in4 + (size_t)b * (IN_D * IN_D * ROW_Q);

    // load one plane's 6 quads (3 rows x 2 quads)
    auto plane_load = [&](int pz, float4 q[6]) {
        const float4* p  = basep + (size_t)pz * (IN_D * ROW_Q);
        const float4* r0 = p + (size_t)yr0 * ROW_Q;
        const float4* r1 = p + (size_t)yr1 * ROW_Q;
        const float4* r2 = p + (size_t)yr2 * ROW_Q;
        q[0] = r0[q0o]; q[1] = r0[q1o];
        q[2] = r1[q0o]; q[3] = r1[q1o];
        q[4] = r2[q0o]; q[5] = r2[q1o];
    };

    // x-lerp one row's quads -> float4 (2 outputs x 2 ch)
    auto rowx = [&](float4 qa, float4 qb) -> float4 {
        float2 e0 = make_float2(qa.x, qa.y);
        float2 e1 = make_float2(qa.z, qa.w);
        float2 e2 = clip ? make_float2(qb.z, qb.w) : make_float2(qb.x, qb.y);
        float2 e3 = make_float2(qb.z, qb.w);
        float2 f0 = (rx == 2u) ? e1 : e0;
        float2 f1 = (rx == 2u) ? e2 : e1;
        float2 g0 = (rx == 0u) ? e0 : ((rx == 1u) ? e1 : e2);
        float2 g1 = (rx == 0u) ? e1 : ((rx == 1u) ? e2 : e3);
        float4 X;
        X.x = f0.x * wxa0 + f1.x * wxa1;
        X.y = f0.y * wxa0 + f1.y * wxa1;
        X.z = g0.x * wxb0 + g1.x * wxb1;
        X.w = g0.y * wxb0 + g1.y * wxb1;
        return X;
    };

    // x+y lerp one plane -> U[3] (y-triple of x-pair float4s)
    auto plane_comp = [&](const float4 q[6], float4 U[3]) {
        float4 X0 = rowx(q[0], q[1]);
        float4 X1 = rowx(q[2], q[3]);
        float4 X2 = rowx(q[4], q[5]);
        U[0] = X0;                            // out y=3yt
        U[1] = f4lerp(X0, X1, THIRD, TWO3);   // out y=3yt+1
        U[2] = f4lerp(X1, X2, TWO3, THIRD);   // out y=3yt+2
    };

    auto nt_store = [&](size_t idx, float4 v) {
        nfloat4 nv;
        nv.x = v.x; nv.y = v.y; nv.z = v.z; nv.w = v.w;
        __builtin_nontemporal_store(nv, (nfloat4*)&out[idx]);
    };

    // ---- z march: triples zt0..zt0+3, carrying shared plane in regs ----
    const int zt0 = zc * ZT_PER_CHUNK;
    float4 qA[6], UA[3];
    plane_load(2 * zt0, qA);
    plane_comp(qA, UA);

    const size_t zs = (size_t)OUT_D * OUT_XP; // one output z-plane
    size_t ob = (((size_t)b * OUT_D + 3 * zt0) * OUT_D + 3 * yt) * OUT_XP + xp;

#pragma unroll
    for (int t = 0; t < ZT_PER_CHUNK; ++t) {
        const int zt = zt0 + t;
        float4 qB[6], qC[6];
        plane_load(2 * zt + 1, qB);                 // all 12 loads issue
        plane_load(min(2 * zt + 2, IN_D - 1), qC);  // before any compute
        float4 UB[3], UC[3];
        plane_comp(qB, UB);
        plane_comp(qC, UC);

#pragma unroll
        for (int yi = 0; yi < 3; ++yi) {
            float4 o0 = UA[yi];                               // z=3zt
            float4 o1 = f4lerp(UA[yi], UB[yi], THIRD, TWO3);  // z=3zt+1
            float4 o2 = f4lerp(UB[yi], UC[yi], TWO3, THIRD);  // z=3zt+2
            size_t oy = ob + (size_t)yi * OUT_XP;
            nt_store(oy,          o0);
            nt_store(oy + zs,     o1);
            nt_store(oy + 2 * zs, o2);
        }
        ob += 3 * zs;
        UA[0] = UC[0]; UA[1] = UC[1]; UA[2] = UC[2];  // carry plane 2(zt+1)
    }
}

extern "C" void kernel_launch(void* const* d_in, const int* in_sizes, int n_in,
                              void* d_out, int out_size, void* d_ws, size_t ws_size,
                              hipStream_t stream) {
    const float4* in4 = (const float4*)d_in[0];
    float4* out = (float4*)d_out;

    dim3 block(OUT_XP, YT_PER_BLOCK, 1);   // 192 threads = 3 waves
    dim3 grid(64 / YT_PER_BLOCK, NZC, 4);  // 32 x 16 x 4 = 2048 blocks
    resize_trilinear_kernel<<<grid, block, 0, stream>>>(in4, out);
}

// Round 5
// 275.565 us; speedup vs baseline: 1.1056x; 1.0108x over previous
//
#include <hip/hip_runtime.h>

// Trilinear resize [4,128,128,128,2] f32 -> [4,192,192,192,2] f32.
// zoom = 1.5 exactly => per axis, weights periodic with period
// 3 outputs / 2 inputs: output o = 3m+r: i0 = 2m + (r==2);
// w0 = {1, 1/3, 2/3}[r]; w1 = 1-w0.
//
// v5: occupancy push. v4's 4-deep fully-unrolled march kept ~18 quads +
// 9 U-vecs live -> VGPR in the 129-256 band -> 8 waves/CU (2/SIMD),
// too few to hide ~900-cycle cold-HBM misses (the harness poison fill
// sweeps L2/L3 every iteration). This version: march of 2 z-triples
// (live set ~110 VGPR) + __launch_bounds__(192,4) to pin VGPR <= 128
// => 16 waves/CU. Grid 4096 blocks (16/CU). Read/store structure
// unchanged from v4: block-private input bricks, aligned 16B quad
// loads (2 per row), register-carried shared plane, NT float4 stores.

#define IN_D  128
#define OUT_D 192
#define OUT_XP 96
#define YT_PER_BLOCK 2   // y-triples per block (block covers 6 output y)
#define ZT_PER_CHUNK 2   // z-triples marched per thread (6 output z)
#define NZC 32           // 64 z-triples / ZT_PER_CHUNK
#define ROW_Q 64         // input row length in float4 units

typedef float nfloat4 __attribute__((ext_vector_type(4)));

__device__ __forceinline__ float4 f4lerp(float4 a, float4 b, float wa, float wb) {
    float4 r;
    r.x = a.x * wa + b.x * wb;
    r.y = a.y * wa + b.y * wb;
    r.z = a.z * wa + b.z * wb;
    r.w = a.w * wa + b.w * wb;
    return r;
}

__global__ __launch_bounds__(192, 4) void resize_trilinear_kernel(
        const float4* __restrict__ in4, float4* __restrict__ out) {
    const int xp = (int)threadIdx.x;                               // 0..95
    const int yt = (int)(blockIdx.x * YT_PER_BLOCK + threadIdx.y); // 0..63
    const int zc = (int)blockIdx.y;                                // 0..31
    const int b  = (int)blockIdx.z;                                // 0..3

    const float THIRD = 0.33333334f;
    const float TWO3  = 0.66666669f;

    // ---- x pair (outputs x = 2*xp, 2*xp+1) ----
    unsigned xo = 2u * (unsigned)xp;
    unsigned mx = xo / 3u;               // magic-mul
    unsigned rx = xo - 3u * mx;
    const int q0o = (int)mx;
    const bool clip = (mx == 63u);       // xp==95: clamp second quad into row
    const int q1o = clip ? 63 : (int)mx + 1;
    float wxa0 = (rx == 0u) ? 1.0f : ((rx == 1u) ? THIRD : TWO3);
    float wxa1 = 1.0f - wxa0;
    float wxb0 = (rx == 0u) ? THIRD : ((rx == 1u) ? TWO3 : 1.0f);
    float wxb1 = 1.0f - wxb0;

    // ---- y triple (outputs y = 3*yt .. 3*yt+2 from rows 2yt..2yt+2) ----
    const int yr0 = 2 * yt;
    const int yr1 = yr0 + 1;
    const int yr2 = min(yr0 + 2, IN_D - 1);

    const float4* basep = in4 + (size_t)b * (IN_D * IN_D * ROW_Q);

    auto plane_load = [&](int pz, float4 q[6]) {
        const float4* p  = basep + (size_t)pz * (IN_D * ROW_Q);
        const float4* r0 = p + (size_t)yr0 * ROW_Q;
        const float4* r1 = p + (size_t)yr1 * ROW_Q;
        const float4* r2 = p + (size_t)yr2 * ROW_Q;
        q[0] = r0[q0o]; q[1] = r0[q1o];
        q[2] = r1[q0o]; q[3] = r1[q1o];
        q[4] = r2[q0o]; q[5] = r2[q1o];
    };

    auto rowx = [&](float4 qa, float4 qb) -> float4 {
        float2 e0 = make_float2(qa.x, qa.y);
        float2 e1 = make_float2(qa.z, qa.w);
        float2 e2 = clip ? make_float2(qb.z, qb.w) : make_float2(qb.x, qb.y);
        float2 e3 = make_float2(qb.z, qb.w);
        float2 f0 = (rx == 2u) ? e1 : e0;
        float2 f1 = (rx == 2u) ? e2 : e1;
        float2 g0 = (rx == 0u) ? e0 : ((rx == 1u) ? e1 : e2);
        float2 g1 = (rx == 0u) ? e1 : ((rx == 1u) ? e2 : e3);
        float4 X;
        X.x = f0.x * wxa0 + f1.x * wxa1;
        X.y = f0.y * wxa0 + f1.y * wxa1;
        X.z = g0.x * wxb0 + g1.x * wxb1;
        X.w = g0.y * wxb0 + g1.y * wxb1;
        return X;
    };

    auto plane_comp = [&](const float4 q[6], float4 U[3]) {
        float4 X0 = rowx(q[0], q[1]);
        float4 X1 = rowx(q[2], q[3]);
        float4 X2 = rowx(q[4], q[5]);
        U[0] = X0;                            // out y=3yt
        U[1] = f4lerp(X0, X1, THIRD, TWO3);   // out y=3yt+1
        U[2] = f4lerp(X1, X2, TWO3, THIRD);   // out y=3yt+2
    };

    auto nt_store = [&](size_t idx, float4 v) {
        nfloat4 nv;
        nv.x = v.x; nv.y = v.y; nv.z = v.z; nv.w = v.w;
        __builtin_nontemporal_store(nv, (nfloat4*)&out[idx]);
    };

    // ---- z march: 2 triples, carrying shared plane in regs ----
    const int zt0 = zc * ZT_PER_CHUNK;
    float4 qA[6], UA[3];
    plane_load(2 * zt0, qA);
    plane_comp(qA, UA);

    const size_t zs = (size_t)OUT_D * OUT_XP; // one output z-plane
    size_t ob = (((size_t)b * OUT_D + 3 * zt0) * OUT_D + 3 * yt) * OUT_XP + xp;

#pragma unroll
    for (int t = 0; t < ZT_PER_CHUNK; ++t) {
        const int zt = zt0 + t;
        float4 qB[6], qC[6];
        plane_load(2 * zt + 1, qB);                 // all 12 loads issue
        plane_load(min(2 * zt + 2, IN_D - 1), qC);  // before any compute
        float4 UB[3], UC[3];
        plane_comp(qB, UB);
        plane_comp(qC, UC);

#pragma unroll
        for (int yi = 0; yi < 3; ++yi) {
            float4 o0 = UA[yi];                               // z=3zt
            float4 o1 = f4lerp(UA[yi], UB[yi], THIRD, TWO3);  // z=3zt+1
            float4 o2 = f4lerp(UB[yi], UC[yi], TWO3, THIRD);  // z=3zt+2
            size_t oy = ob + (size_t)yi * OUT_XP;
            nt_store(oy,          o0);
            nt_store(oy + zs,     o1);
            nt_store(oy + 2 * zs, o2);
        }
        ob += 3 * zs;
        UA[0] = UC[0]; UA[1] = UC[1]; UA[2] = UC[2];  // carry plane 2(zt+1)
    }
}

extern "C" void kernel_launch(void* const* d_in, const int* in_sizes, int n_in,
                              void* d_out, int out_size, void* d_ws, size_t ws_size,
                              hipStream_t stream) {
    const float4* in4 = (const float4*)d_in[0];
    float4* out = (float4*)d_out;

    dim3 block(OUT_XP, YT_PER_BLOCK, 1);   // 192 threads = 3 waves
    dim3 grid(64 / YT_PER_BLOCK, NZC, 4);  // 32 x 32 x 4 = 4096 blocks
    resize_trilinear_kernel<<<grid, block, 0, stream>>>(in4, out);
}